// Round 2
// baseline (1103.358 us; speedup 1.0000x reference)
//
#include <hip/hip_runtime.h>

#define GRIDS  8400
#define TNB    256
#define NCV    80
#define TOPKV  13
#define EPSF   1e-9f
#define NWORDS 263   // ceil(8400/32)

__global__ __launch_bounds__(256) void taa_fused(
    const float* __restrict__ pd_scores,
    const float* __restrict__ pd_bboxes,
    const float* __restrict__ anc,
    const int*   __restrict__ gt_labels,
    const float* __restrict__ gt_bboxes,
    float* __restrict__ out_labels,
    float* __restrict__ out_bboxes,
    float* __restrict__ out_scores,
    float* __restrict__ out_mask)
{
    __shared__ float smet[GRIDS];
    __shared__ unsigned bitmap[NWORDS];
    __shared__ float wv[4];
    __shared__ int   wi[4];
    __shared__ int   sel_idx[TOPKV];
    __shared__ float sel_val[TOPKV];
    __shared__ float sel_am[TOPKV];
    __shared__ float sel_ov[TOPKV];
    __shared__ int   sel_in[TOPKV];

    const int t   = blockIdx.x;
    const int tid = threadIdx.x;

    const float4 gbb = reinterpret_cast<const float4*>(gt_bboxes)[t];
    const float gx1 = gbb.x, gy1 = gbb.y, gx2 = gbb.z, gy2 = gbb.w;
    const int   lab = gt_labels[t];
    const float garea = fmaxf(gx2-gx1, 0.f) * fmaxf(gy2-gy1, 0.f);

    const float4* pb   = reinterpret_cast<const float4*>(pd_bboxes) + (size_t)t*GRIDS;
    const float2* anc2 = reinterpret_cast<const float2*>(anc);
    const float*  ps   = pd_scores + (size_t)t*GRIDS*NCV + lab;

    // ---- Pass 1: masked align metric into LDS (arithmetic identical to R1) ----
    #pragma unroll 4
    for (int g = tid; g < GRIDS; g += 256) {
        float2 a = anc2[g];
        float ax = a.x, ay = a.y;
        float dmin = fminf(fminf(ax-gx1, ay-gy1), fminf(gx2-ax, gy2-ay));
        float4 p = pb[g];
        float ix1 = fmaxf(gx1, p.x), iy1 = fmaxf(gy1, p.y);
        float ix2 = fminf(gx2, p.z), iy2 = fminf(gy2, p.w);
        float ov  = fmaxf(ix2-ix1, 0.f) * fmaxf(iy2-iy1, 0.f);
        float pa  = fmaxf(p.z-p.x, 0.f) * fmaxf(p.w-p.y, 0.f);
        float iou = ov / (garea + pa - ov + EPSF);
        float sc  = ps[(size_t)g*NCV];
        float i2  = iou*iou;
        float m   = sc * (i2*i2*i2);
        smet[g] = (dmin > EPSF) ? m : 0.f;
    }
    __syncthreads();

    // ---- Top-13: iterated stable argmax; wave-shuffle reduce (2 barriers/iter) ----
    for (int k = 0; k < TOPKV; ++k) {
        float bv = -1.f; int bi = GRIDS;
        for (int g = tid; g < GRIDS; g += 256) {
            float v = smet[g];
            if (v > bv) { bv = v; bi = g; }   // in-thread g increasing: first-equal wins
        }
        #pragma unroll
        for (int off = 32; off > 0; off >>= 1) {
            float v2 = __shfl_down(bv, off);
            int   i2 = __shfl_down(bi, off);
            if (v2 > bv || (v2 == bv && i2 < bi)) { bv = v2; bi = i2; }
        }
        if ((tid & 63) == 0) { wv[tid >> 6] = bv; wi[tid >> 6] = bi; }
        __syncthreads();
        if (tid == 0) {
            float fv = wv[0]; int fi = wi[0];
            #pragma unroll
            for (int w = 1; w < 4; ++w) {
                float v2 = wv[w]; int i2 = wi[w];
                if (v2 > fv || (v2 == fv && i2 < fi)) { fv = v2; fi = i2; }
            }
            sel_idx[k] = fi; sel_val[k] = fv;
            smet[fi] = -1.f;   // knock out (metrics >= 0, never re-selected)
        }
        __syncthreads();
    }

    // ---- Tail: recompute in_gts / iou at the 13 selected anchors ----
    if (tid < TOPKV) {
        int g = sel_idx[tid];
        float2 a = anc2[g];
        float ax = a.x, ay = a.y;
        float dmin = fminf(fminf(ax-gx1, ay-gy1), fminf(gx2-ax, gy2-ay));
        bool ing = dmin > EPSF;
        float4 p = pb[g];
        float ix1 = fmaxf(gx1, p.x), iy1 = fmaxf(gy1, p.y);
        float ix2 = fminf(gx2, p.z), iy2 = fminf(gy2, p.w);
        float ov  = fmaxf(ix2-ix1, 0.f) * fmaxf(iy2-iy1, 0.f);
        float pa  = fmaxf(p.z-p.x, 0.f) * fmaxf(p.w-p.y, 0.f);
        float iou = ov / (garea + pa - ov + EPSF);
        sel_in[tid] = ing ? 1 : 0;
        sel_am[tid] = ing ? sel_val[tid] : 0.f;  // am = align_metric * mask_pos
        sel_ov[tid] = ing ? iou : 0.f;           // overlaps * mask_pos
    }
    // zero the membership bitmap while the tail runs
    for (int w = tid; w < NWORDS; w += 256) bitmap[w] = 0u;
    __syncthreads();

    // ---- Norm + bitmap: park norm values in the dead smet[] slots ----
    if (tid < TOPKV && sel_in[tid]) {
        float pa = 0.f, po = 0.f;
        #pragma unroll
        for (int k = 0; k < TOPKV; ++k) {
            pa = fmaxf(pa, sel_am[k]);
            po = fmaxf(po, sel_ov[k]);
        }
        float norm = sel_am[tid] * po / (pa + EPSF);
        int g = sel_idx[tid];
        smet[g] = norm;                              // only read where bit is set
        atomicOr(&bitmap[g >> 5], 1u << (g & 31));
    }
    __syncthreads();

    // ---- Fill phase: write FINAL values for this row's entire output slice ----
    const float labf = (float)lab;
    const float4 z4  = {0.f, 0.f, 0.f, 0.f};
    const float4 gb4 = {gx1, gy1, gx2, gy2};
    float4* lab4 = reinterpret_cast<float4*>(out_labels + (size_t)t*GRIDS);
    float4* msk4 = reinterpret_cast<float4*>(out_mask   + (size_t)t*GRIDS);
    float4* bb4  = reinterpret_cast<float4*>(out_bboxes + (size_t)t*GRIDS*4);
    float4* sc4  = reinterpret_cast<float4*>(out_scores + (size_t)t*GRIDS*NCV);

    // labels + mask: 2100 float4 chunks each
    for (int c = tid; c < GRIDS/4; c += 256) {
        unsigned b = (bitmap[c >> 3] >> ((c & 7) * 4)) & 0xFu;
        float4 lv = z4, mv = z4;
        if (b & 1u) { lv.x = labf; mv.x = 1.f; }
        if (b & 2u) { lv.y = labf; mv.y = 1.f; }
        if (b & 4u) { lv.z = labf; mv.z = 1.f; }
        if (b & 8u) { lv.w = labf; mv.w = 1.f; }
        lab4[c] = lv;
        msk4[c] = mv;
    }
    // bboxes: 8400 float4 chunks
    for (int g = tid; g < GRIDS; g += 256) {
        bool s = (bitmap[g >> 5] >> (g & 31)) & 1u;
        bb4[g] = s ? gb4 : z4;
    }
    // scores: 168000 float4 chunks; chunk c covers anchor g=c/20, classes 4*(c%20)..+3
    for (int c = tid; c < (GRIDS*NCV)/4; c += 256) {
        unsigned g = (unsigned)c / 20u;
        float4 v = z4;
        if ((bitmap[g >> 5] >> (g & 31)) & 1u) {
            int cls0 = (c - (int)g*20) * 4;
            int d = lab - cls0;
            if ((unsigned)d < 4u) {
                float nv = smet[g];
                if (d == 0) v.x = nv;
                else if (d == 1) v.y = nv;
                else if (d == 2) v.z = nv;
                else v.w = nv;
            }
        }
        sc4[c] = v;
    }
}

extern "C" void kernel_launch(void* const* d_in, const int* in_sizes, int n_in,
                              void* d_out, int out_size, void* d_ws, size_t ws_size,
                              hipStream_t stream)
{
    const float* pd_scores = (const float*)d_in[0];
    const float* pd_bboxes = (const float*)d_in[1];
    const float* anc       = (const float*)d_in[2];
    const int*   gt_labels = (const int*)d_in[3];
    const float* gt_bboxes = (const float*)d_in[4];
    float* out = (float*)d_out;

    float* out_labels = out;
    float* out_bboxes = out_labels + (size_t)TNB*GRIDS;
    float* out_scores = out_bboxes + (size_t)TNB*GRIDS*4;
    float* out_mask   = out_scores + (size_t)TNB*GRIDS*NCV;

    taa_fused<<<TNB, 256, 0, stream>>>(pd_scores, pd_bboxes, anc, gt_labels, gt_bboxes,
                                       out_labels, out_bboxes, out_scores, out_mask);
}